// Round 10
// baseline (144.140 us; speedup 1.0000x reference)
//
#include <hip/hip_runtime.h>

// SpiralConv conv block: per-channel complex first-order recurrence
//   h[n] = c*h[n-1] + x[n],  h[-1] = last_conv_init[d],  out = Re(h)*x
// with c_d = exp(-exp(lmlg_d)) * e^{i*theta_d}.
//
// R14: R13 + double-buffered LDS pipeline. R13 (56us, 3.1 TB/s, occ 64%,
// coalesced 1KB granules, 0 conflicts) exposed a ~50% memory duty cycle:
// stage->drain->barrier->compute in lockstep leaves zero bytes in flight
// during compute; 2 phase-offset blocks/CU -> measured 3.1/6.3. Fix: 8-row
// chunks, two 8KB buffers per group; issue chunk i+1's loads, compute
// chunk i, ds_write prefetch, one barrier (phase 3: +1 for writeback vs
// unstage ordering). LDS stays 70KB -> 2 blocks/CU. Geometry unchanged:
// 512 blk x 1024 thr, 4 groups x 256 ch, W=256 truncated warmup (error
// ~1e-4 << 0.0625 tol; T0<=256 blocks exact).

#define L_    4096
#define B_    4
#define D_    1024
#define BD_   (B_ * D_)       // 4096 floats per time step
#define SPAN_ 128             // output steps per block
#define W_    256             // truncated warmup length
#define NLG_  (L_ / SPAN_)    // 32 time-groups
#define NBLK_ (NLG_ * B_ * 4) // 512 blocks

// 8-row x 256-ch chunk movers. thread ch handles elements e=ch and e=256+ch
// of the 512-float4 chunk: row = e>>6 (0..7), c4 = e&63. Wave-request =
// 64 consecutive float4 = 1KB contiguous.
__device__ __forceinline__ void ld_chunk8(const float* __restrict__ g,
                                          int ch, float4& v0, float4& v1) {
  const int r0 = ch >> 6,        c0 = ch & 63;
  const int r1 = (256 + ch) >> 6, c1 = ch & 63;
  v0 = *((const float4*)(g + (size_t)r0 * BD_) + c0);
  v1 = *((const float4*)(g + (size_t)r1 * BD_) + c1);
}
__device__ __forceinline__ void st_chunk8(float* __restrict__ tile,
                                          int ch, float4 v0, float4 v1) {
  const int r0 = ch >> 6,         c0 = ch & 63;
  const int r1 = (256 + ch) >> 6, c1 = ch & 63;
  *((float4*)(tile + r0 * 256) + c0) = v0;
  *((float4*)(tile + r1 * 256) + c1) = v1;
}
__device__ __forceinline__ void unst_chunk8(float* __restrict__ g,
                                            const float* __restrict__ tile,
                                            int ch) {
  const int r0 = ch >> 6,         c0 = ch & 63;
  const int r1 = (256 + ch) >> 6, c1 = ch & 63;
  *((float4*)(g + (size_t)r0 * BD_) + c0) =
      *((const float4*)(tile + r0 * 256) + c0);
  *((float4*)(g + (size_t)r1 * BD_) + c1) =
      *((const float4*)(tile + r1 * 256) + c1);
}

__global__ __launch_bounds__(1024, 4) void sc_one(
    const float* __restrict__ x,
    const float* __restrict__ lmlg,
    const float* __restrict__ theta,
    const float* __restrict__ init,
    float* __restrict__ out) {
  __shared__ float  Tl[2][4][8 * 256];   // double-buffered group tiles (64 KB)
  __shared__ float2 S[3 * 256];          // group summaries (6 KB)

  const int tid = threadIdx.x;
  const int ch  = tid & 255;
  const int g   = tid >> 8;       // 0..3 (wave-uniform)
  const int bid = blockIdx.x;
  const int db  = bid & 3;
  const int b   = (bid >> 2) & 3;
  const int lg  = bid >> 4;
  const int d   = (db << 8) + ch;

  const int T0  = lg * SPAN_;
  const int wst = (T0 >= W_) ? (T0 - W_) : 0;   // walk start (clamped)
  const int tot = T0 + SPAN_ - wst;             // 128 / 256 / 384
  const int q   = tot >> 2;                     // 32 / 64 / 96
  const int gs  = wst + g * q;                  // this group's start step
  const int NC  = q >> 3;                       // 4 / 8 / 12 chunks of 8 rows

  // per-channel decay*rotation c and group jump Cq = c^q
  const float lgv = lmlg[d], th = theta[d];
  const float e   = expf(lgv);
  const float gam = expf(-e);
  const float cr  = gam * cosf(th), ci = gam * sinf(th);
  const float qf  = (float)q;
  const float Gq  = expf(-e * qf);
  const float Cqr = Gq * cosf(th * qf), Cqi = Gq * sinf(th * qf);

  // this group's chunk-0 base in x/out (row gs, slice db, batch b)
  const float* xg = x   + (size_t)b * D_ + (db << 8) + (size_t)gs * BD_;
  float*       og = out + (size_t)b * D_ + (db << 8) + (size_t)gs * BD_;

  // ---- phase 1: local summary from zero state (groups 0..2 only) ----
  if (g < 3) {
    float4 a0, a1;
    ld_chunk8(xg, ch, a0, a1);
    st_chunk8(&Tl[0][g][0], ch, a0, a1);
  }
  __syncthreads();
  float sr = 0.f, si = 0.f;
  int cur = 0;
  for (int i = 0; i < NC; ++i) {
    float4 w0, w1;
    const bool pf = (g < 3) && (i + 1 < NC);
    if (pf) ld_chunk8(xg + (size_t)(i + 1) * 8 * BD_, ch, w0, w1);
    if (g < 3) {
      const float* tp = &Tl[cur][g][0];
#pragma unroll
      for (int r = 0; r < 8; ++r) {
        float xv = tp[r * 256 + ch];
        float nr = fmaf(cr, sr, fmaf(-ci, si, xv));
        float ni = fmaf(cr, si, ci * sr);
        sr = nr; si = ni;
      }
    }
    if (pf) st_chunk8(&Tl[cur ^ 1][g][0], ch, w0, w1);
    __syncthreads();
    cur ^= 1;
  }
  if (g < 3) S[g * 256 + ch] = make_float2(sr, si);
  __syncthreads();

  // ---- phase 2: entering state for this group ----
  float hr = (wst == 0) ? init[d] : 0.f;
  float hi = 0.f;
  for (int j = 0; j < g; ++j) {
    float2 s = S[j * 256 + ch];
    float nr = fmaf(Cqr, hr, fmaf(-Cqi, hi, s.x));
    float ni = fmaf(Cqr, hi, fmaf( Cqi, hr, s.y));
    hr = nr; hi = ni;
  }

  // ---- phase 3: replay + store for output-overlapping groups ----
  const bool part = (gs + q > T0);
  const int  skip = (part && T0 > gs) ? (T0 - gs) : 0;   // 0 or 64
  if (part) {
    float4 a0, a1;
    ld_chunk8(xg, ch, a0, a1);
    st_chunk8(&Tl[0][g][0], ch, a0, a1);
  }
  __syncthreads();
  cur = 0;
  for (int i = 0; i < NC; ++i) {
    float4 w0, w1;
    const bool pf = part && (i + 1 < NC);
    const bool wb = part && (i * 8 >= skip);   // chunk-uniform store flag
    if (pf) ld_chunk8(xg + (size_t)(i + 1) * 8 * BD_, ch, w0, w1);
    if (part) {
      float* tp = &Tl[cur][g][0];
#pragma unroll
      for (int r = 0; r < 8; ++r) {
        float xv = tp[r * 256 + ch];
        float nr = fmaf(cr, hr, fmaf(-ci, hi, xv));
        float ni = fmaf(cr, hi, ci * hr);
        hr = nr; hi = ni;
        if (wb) tp[r * 256 + ch] = nr * xv;    // own (r,ch): no hazard
      }
    }
    __syncthreads();   // writebacks visible before cross-column unstage
    if (wb) unst_chunk8(og + (size_t)i * 8 * BD_, &Tl[cur][g][0], ch);
    if (pf) st_chunk8(&Tl[cur ^ 1][g][0], ch, w0, w1);
    __syncthreads();
    cur ^= 1;
  }
}

// ------------------------------------------------------------- fallback ----
// ws-free fully sequential per-column scan (kept for safety; unused path).
__global__ __launch_bounds__(256) void sc_full(
    const float* __restrict__ x, const float* __restrict__ lmlg,
    const float* __restrict__ theta, const float* __restrict__ init,
    float* __restrict__ out) {
  const int idx = blockIdx.x * 256 + threadIdx.x;   // column b*D+d
  const int d   = idx & (D_ - 1);
  float g = expf(-expf(lmlg[d]));
  float cr = g * cosf(theta[d]), ci = g * sinf(theta[d]);
  float hr = init[d], hi = 0.f;
  const float* xp = x + idx;
  float*       op = out + idx;
  for (int n = 0; n < L_; ++n) {
    float xv = xp[(size_t)n * BD_];
    float nr = fmaf(cr, hr, fmaf(-ci, hi, xv));
    float ni = fmaf(cr, hi, ci * hr);
    hr = nr; hi = ni;
    op[(size_t)n * BD_] = nr * xv;
  }
}

// ---------------------------------------------------------------------------
extern "C" void kernel_launch(void* const* d_in, const int* in_sizes, int n_in,
                              void* d_out, int out_size, void* d_ws, size_t ws_size,
                              hipStream_t stream) {
  const float* x     = (const float*)d_in[0];
  const float* lmlg  = (const float*)d_in[1];
  const float* theta = (const float*)d_in[2];
  const float* init  = (const float*)d_in[3];
  float* out = (float*)d_out;
  (void)d_ws; (void)ws_size;

  sc_one<<<NBLK_, 1024, 0, stream>>>(x, lmlg, theta, init, out);
}

// Round 13
// 136.583 us; speedup vs baseline: 1.0553x; 1.0553x over previous
//
#include <hip/hip_runtime.h>
#include <stdint.h>

// SpiralConv conv block: per-channel complex first-order recurrence
//   h[n] = c*h[n-1] + x[n],  h[-1] = last_conv_init[d],  out = Re(h)*x
// with c_d = exp(-exp(lmlg_d)) * e^{i*theta_d}.
//
// R17: two-dispatch exact scan (R7 structure, best total 134.3) + two fixes:
//  1) inline-asm global_load_dword batches with counted s_waitcnt vmcnt(8)
//     + sched_barrier(0): compiler provably sinks register prefetches
//     (R9/R10/R14: VGPR 20-28, BW pinned 2.9 TB/s = 1 req/wave in flight;
//     need ~9.2 KB/CU in flight, had ~8 KB). asm volatile loads cannot be
//     sunk -> 16 loads/thread in flight. global_load_lds is abandoned
//     (two consecutive container failures with it; suspect AS-cast hang).
//  2) K2 stores staged through LDS[32][256] and written cooperatively as
//     float4 (1 KB/wave contiguous = fill-kernel pattern) instead of
//     scalar 256B-granule strided stores.
// Budget model: ~85us fixed harness overhead + kernels; R7 kernels ~48us.

#define L_  4096
#define B_  4
#define D_  1024
#define BD_ (B_ * D_)      // 4096 floats per time step
#define NC_ 128
#define CH_ (L_ / NC_)     // 32

#define GLD(dst, addr) \
  asm volatile("global_load_dword %0, %1, off" : "=v"(dst) : "v"(addr) : "memory")
#define WAITV8() asm volatile("s_waitcnt vmcnt(8)" ::: "memory")
#define WAITV0() asm volatile("s_waitcnt vmcnt(0)" ::: "memory")
#define SCHEDB() __builtin_amdgcn_sched_barrier(0)

// ---------------------------------------------------------------- K1 -------
// One block per (chunk k, batch b, 256-ch slice db); 1 channel/thread.
// Chunk summary s = recurrence over CH=32 steps from zero state.
// 4 batches of 8 asm loads, 2 register sets, 2 batches in flight.
__global__ __launch_bounds__(256) void sc_sum(
    const float* __restrict__ x,
    const float* __restrict__ lmlg,
    const float* __restrict__ theta,
    float2* __restrict__ ws) {
  const int t   = threadIdx.x;
  const int bid = blockIdx.x;
  const int db  = bid & 3;
  const int b   = (bid >> 2) & (B_ - 1);
  const int k   = bid >> 4;
  const int d   = (db << 8) + t;

  const float lg = lmlg[d], th = theta[d];
  const float g  = expf(-expf(lg));
  const float cr = g * cosf(th), ci = g * sinf(th);

  const float* xp = x + (size_t)k * CH_ * BD_ + (size_t)b * D_ + d;
  float xa[8], xb[8];
#pragma unroll
  for (int u = 0; u < 8; ++u) GLD(xa[u], xp + (size_t)u * BD_);
#pragma unroll
  for (int u = 0; u < 8; ++u) GLD(xb[u], xp + (size_t)(8 + u) * BD_);

  float sr = 0.f, si = 0.f;
  WAITV8(); SCHEDB();
#pragma unroll
  for (int u = 0; u < 8; ++u) {          // consume batch 0 (xa)
    float nr = fmaf(cr, sr, fmaf(-ci, si, xa[u]));
    float ni = fmaf(cr, si, ci * sr);
    sr = nr; si = ni;
  }
#pragma unroll
  for (int u = 0; u < 8; ++u) GLD(xa[u], xp + (size_t)(16 + u) * BD_);
  WAITV8(); SCHEDB();
#pragma unroll
  for (int u = 0; u < 8; ++u) {          // consume batch 1 (xb)
    float nr = fmaf(cr, sr, fmaf(-ci, si, xb[u]));
    float ni = fmaf(cr, si, ci * sr);
    sr = nr; si = ni;
  }
#pragma unroll
  for (int u = 0; u < 8; ++u) GLD(xb[u], xp + (size_t)(24 + u) * BD_);
  WAITV8(); SCHEDB();
#pragma unroll
  for (int u = 0; u < 8; ++u) {          // consume batch 2 (xa)
    float nr = fmaf(cr, sr, fmaf(-ci, si, xa[u]));
    float ni = fmaf(cr, si, ci * sr);
    sr = nr; si = ni;
  }
  WAITV0(); SCHEDB();
#pragma unroll
  for (int u = 0; u < 8; ++u) {          // consume batch 3 (xb)
    float nr = fmaf(cr, sr, fmaf(-ci, si, xb[u]));
    float ni = fmaf(cr, si, ci * sr);
    sr = nr; si = ni;
  }

  ws[(size_t)(k * B_ + b) * D_ + d] = make_float2(sr, si);
}

// ---------------------------------------------------------------- K2 -------
// Prefix-scan summaries 0..k-1 (C^2 jumps, L2-hot), replay the chunk with
// asm-pipelined loads (x is L3-hot after K1), stage results in LDS, then
// store cooperatively as float4 (1 KB/wave contiguous).
__global__ __launch_bounds__(256) void sc_out(
    const float* __restrict__ x,
    const float* __restrict__ lmlg,
    const float* __restrict__ theta,
    const float* __restrict__ init,
    const float2* __restrict__ ws,
    float* __restrict__ out) {
  __shared__ float Ro[CH_][256];   // 32 KB result staging

  const int t   = threadIdx.x;
  const int bid = blockIdx.x;
  const int db  = bid & 3;
  const int b   = (bid >> 2) & (B_ - 1);
  const int k   = bid >> 4;
  const int d   = (db << 8) + t;

  const float lg = lmlg[d], th = theta[d];
  const float e  = expf(lg);
  const float g  = expf(-e);
  const float cr = g * cosf(th), ci = g * sinf(th);

  // jump factor C = c^CH (from params; matches prior rounds' numerics)
  const float chf = (float)CH_;
  const float G   = expf(-e * chf);
  const float Cr  = G * cosf(th * chf), Ci = G * sinf(th * chf);

  // carry into chunk k: h = init; for kk<k: h = C*h + s[kk]  (C^2 jumps)
  float hr = init[d], hi = 0.f;
  const float2* sp = ws + (size_t)b * D_ + d;
  {
    const float C2r = fmaf(Cr, Cr, -Ci * Ci);
    const float C2i = 2.f * Cr * Ci;
    int kk = 0;
    for (; kk + 2 <= k; kk += 2) {
      float2 s0 = sp[(size_t)kk * BD_];
      float2 s1 = sp[(size_t)(kk + 1) * BD_];
      float ur = fmaf(Cr, s0.x, fmaf(-Ci, s0.y, s1.x));
      float ui = fmaf(Cr, s0.y, fmaf( Ci, s0.x, s1.y));
      float nr = fmaf(C2r, hr, fmaf(-C2i, hi, ur));
      float ni = fmaf(C2r, hi, fmaf( C2i, hr, ui));
      hr = nr; hi = ni;
    }
    if (kk < k) {
      float2 s = sp[(size_t)kk * BD_];
      float nr = fmaf(Cr, hr, fmaf(-Ci, hi, s.x));
      float ni = fmaf(Cr, hi, fmaf( Ci, hr, s.y));
      hr = nr; hi = ni;
    }
  }

  // replay recurrence over this chunk; results -> LDS
  const float* xp = x + (size_t)k * CH_ * BD_ + (size_t)b * D_ + d;
  float xa[8], xb[8];
#pragma unroll
  for (int u = 0; u < 8; ++u) GLD(xa[u], xp + (size_t)u * BD_);
#pragma unroll
  for (int u = 0; u < 8; ++u) GLD(xb[u], xp + (size_t)(8 + u) * BD_);

  WAITV8(); SCHEDB();
#pragma unroll
  for (int u = 0; u < 8; ++u) {
    float nr = fmaf(cr, hr, fmaf(-ci, hi, xa[u]));
    float ni = fmaf(cr, hi, ci * hr);
    hr = nr; hi = ni;
    Ro[u][t] = nr * xa[u];
  }
#pragma unroll
  for (int u = 0; u < 8; ++u) GLD(xa[u], xp + (size_t)(16 + u) * BD_);
  WAITV8(); SCHEDB();
#pragma unroll
  for (int u = 0; u < 8; ++u) {
    float nr = fmaf(cr, hr, fmaf(-ci, hi, xb[u]));
    float ni = fmaf(cr, hi, ci * hr);
    hr = nr; hi = ni;
    Ro[8 + u][t] = nr * xb[u];
  }
#pragma unroll
  for (int u = 0; u < 8; ++u) GLD(xb[u], xp + (size_t)(24 + u) * BD_);
  WAITV8(); SCHEDB();
#pragma unroll
  for (int u = 0; u < 8; ++u) {
    float nr = fmaf(cr, hr, fmaf(-ci, hi, xa[u]));
    float ni = fmaf(cr, hi, ci * hr);
    hr = nr; hi = ni;
    Ro[16 + u][t] = nr * xa[u];
  }
  WAITV0(); SCHEDB();
#pragma unroll
  for (int u = 0; u < 8; ++u) {
    float nr = fmaf(cr, hr, fmaf(-ci, hi, xb[u]));
    float ni = fmaf(cr, hi, ci * hr);
    hr = nr; hi = ni;
    Ro[24 + u][t] = nr * xb[u];
  }

  __syncthreads();

  // cooperative float4 stores: wave w stores rows w, w+4, ..., w+28;
  // lane stores float4 #lane of the row -> 1 KB contiguous per wave-op.
  float* ob = out + (size_t)k * CH_ * BD_ + (size_t)b * D_ + (db << 8);
  const int w    = t >> 6;
  const int lane = t & 63;
#pragma unroll
  for (int u = 0; u < 8; ++u) {
    const int r = w + u * 4;
    float4 v = *(const float4*)&Ro[r][lane * 4];
    *((float4*)(ob + (size_t)r * BD_) + lane) = v;
  }
}

// ------------------------------------------------------------- fallback ----
// ws-free fully sequential per-column scan (used only if ws_size is tiny).
__global__ __launch_bounds__(256) void sc_full(
    const float* __restrict__ x, const float* __restrict__ lmlg,
    const float* __restrict__ theta, const float* __restrict__ init,
    float* __restrict__ out) {
  const int idx = blockIdx.x * 256 + threadIdx.x;   // column b*D+d
  const int d   = idx & (D_ - 1);
  float g = expf(-expf(lmlg[d]));
  float cr = g * cosf(theta[d]), ci = g * sinf(theta[d]);
  float hr = init[d], hi = 0.f;
  const float* xp = x + idx;
  float*       op = out + idx;
  for (int n = 0; n < L_; ++n) {
    float xv = xp[(size_t)n * BD_];
    float nr = fmaf(cr, hr, fmaf(-ci, hi, xv));
    float ni = fmaf(cr, hi, ci * hr);
    hr = nr; hi = ni;
    op[(size_t)n * BD_] = nr * xv;
  }
}

// ---------------------------------------------------------------------------
extern "C" void kernel_launch(void* const* d_in, const int* in_sizes, int n_in,
                              void* d_out, int out_size, void* d_ws, size_t ws_size,
                              hipStream_t stream) {
  const float* x     = (const float*)d_in[0];
  const float* lmlg  = (const float*)d_in[1];
  const float* theta = (const float*)d_in[2];
  const float* init  = (const float*)d_in[3];
  float*  out = (float*)d_out;
  float2* ws  = (float2*)d_ws;

  const size_t need = (size_t)NC_ * B_ * D_ * sizeof(float2);   // 4 MiB
  if (ws_size >= need) {
    const int grid = NC_ * B_ * (D_ / 256);   // 2048 blocks
    sc_sum<<<grid, 256, 0, stream>>>(x, lmlg, theta, ws);
    sc_out<<<grid, 256, 0, stream>>>(x, lmlg, theta, init, ws, out);
  } else {
    sc_full<<<BD_ / 256, 256, 0, stream>>>(x, lmlg, theta, init, out);
  }
}